// Round 4
// baseline (68.462 us; speedup 1.0000x reference)
//
#include <hip/hip_runtime.h>
#include <hip/hip_bf16.h>
#include <math.h>

// QCONV2d 5x5: out[b,c,h,w] = prod_{p=1..24} cos(x_patch[p] + w[p])
// cos(x+w) = cos(x)cos(w) - sin(x)sin(w): sincos(pixel) once -> LDS (SoA:
// separate cos/sin planes so ds_read_b128 yields 4 consecutive-column values,
// operand-shaped for packed v_pk_fma_f32 math). sincos(w) once per lane ->
// v_readlane -> 50 SGPRs. Each thread: 4 cols x 4 rows = 16 outputs, product
// math on float2 ext-vectors (packed dual-f32 pipe). Zero pad => (cos,sin)=(1,0).

#define SMR   68        // 64 rows + 2 halo each side
#define SMSTR 72        // row stride in floats (288 B, 16B-multiple)

typedef float v2f __attribute__((ext_vector_type(2)));

__device__ __forceinline__ float rdlane(float v, int lane) {
    return __uint_as_float(__builtin_amdgcn_readlane(__float_as_uint(v), lane));
}

__global__ __launch_bounds__(256)
void qconv5x5_kernel(const float* __restrict__ x, const float* __restrict__ w,
                     float* __restrict__ out)
{
    __shared__ alignas(16) float smc[SMR][SMSTR];  // cos plane, 19.1 KB
    __shared__ alignas(16) float sms[SMR][SMSTR];  // sin plane, 19.1 KB

    const int tid   = threadIdx.x;
    const int plane = blockIdx.x;            // 512 planes, one per block

    // --- w-trig: one sincos per lane, broadcast via readlane -> SGPRs ---
    const int lane = tid & 63;
    float sv, cv;
    __sincosf(w[lane < 25 ? lane : 0], &sv, &cv);
    float cw[25], sw[25];
#pragma unroll
    for (int p = 0; p < 25; ++p) {
        cw[p] = rdlane(cv, p);
        sw[p] = rdlane(sv, p);
    }

    // --- stage whole plane + halo: rows/cols [-2, 65]; OOB -> (1,0) ---
    const float* xp = x + plane * 64 * 64;
    for (int i = tid; i < SMR * SMR; i += 256) {
        const int rr = i / SMR;
        const int cc = i - rr * SMR;
        const int gr = rr - 2;
        const int gc = cc - 2;
        float c = 1.0f, s = 0.0f;
        if ((unsigned)gr < 64u && (unsigned)gc < 64u) {
            __sincosf(xp[gr * 64 + gc], &s, &c);
        }
        smc[rr][cc] = c;
        sms[rr][cc] = s;
    }
    __syncthreads();

    // --- compute: thread -> 4 cols (4ci..4ci+3) x 4 rows (4rq..4rq+3) ---
    const int ci = tid & 15;     // 16 col groups
    const int rq = tid >> 4;     // 16 row groups

    v2f prodA[4], prodB[4];      // cols {0,1} and {2,3} of the 4-col group
#pragma unroll
    for (int ro = 0; ro < 4; ++ro) { prodA[ro] = (v2f)1.0f; prodB[ro] = (v2f)1.0f; }

    // Output row r uses staged rows r..r+4 (staged row 0 = global row -2).
    // 8 neighborhood rows feed the 4 output rows.
#pragma unroll
    for (int nr = 0; nr < 8; ++nr) {
        const int tr = rq * 4 + nr;
        // cols 4ci..4ci+7 of cos and sin: 4 aligned b128 reads
        const float4 c0 = *reinterpret_cast<const float4*>(&smc[tr][4 * ci]);
        const float4 c1 = *reinterpret_cast<const float4*>(&smc[tr][4 * ci + 4]);
        const float4 s0 = *reinterpret_cast<const float4*>(&sms[tr][4 * ci]);
        const float4 s1 = *reinterpret_cast<const float4*>(&sms[tr][4 * ci + 4]);
        const float cwin[8] = {c0.x, c0.y, c0.z, c0.w, c1.x, c1.y, c1.z, c1.w};
        const float swin[8] = {s0.x, s0.y, s0.z, s0.w, s1.x, s1.y, s1.z, s1.w};
#pragma unroll
        for (int ro = 0; ro < 4; ++ro) {
            const int di = nr - ro;
            if (di < 0 || di > 4) continue;
#pragma unroll
            for (int dj = 0; dj < 5; ++dj) {
                const int p = di * 5 + dj;
                if (p == 0) continue;        // reference product is p=1..24
                v2f ca; ca.x = cwin[dj];     ca.y = cwin[dj + 1];
                v2f cb; cb.x = cwin[dj + 2]; cb.y = cwin[dj + 3];
                v2f sa; sa.x = swin[dj];     sa.y = swin[dj + 1];
                v2f sb; sb.x = swin[dj + 2]; sb.y = swin[dj + 3];
                prodA[ro] *= (ca * cw[p] - sa * sw[p]);   // -> v_pk_mul/v_pk_fma
                prodB[ro] *= (cb * cw[p] - sb * sw[p]);
            }
        }
    }

    // --- store: float4 per output row, 16B/lane coalesced ---
    float* op = out + plane * 64 * 64 + (rq * 4) * 64 + 4 * ci;
#pragma unroll
    for (int ro = 0; ro < 4; ++ro) {
        float4 v = make_float4(prodA[ro].x, prodA[ro].y, prodB[ro].x, prodB[ro].y);
        *reinterpret_cast<float4*>(op + ro * 64) = v;
    }
}

extern "C" void kernel_launch(void* const* d_in, const int* in_sizes, int n_in,
                              void* d_out, int out_size, void* d_ws, size_t ws_size,
                              hipStream_t stream) {
    const float* x = (const float*)d_in[0];   // [32,16,64,64] f32
    const float* w = (const float*)d_in[1];   // [25] f32
    float* out = (float*)d_out;               // [32,16,64,64] f32
    (void)in_sizes; (void)n_in; (void)out_size; (void)d_ws; (void)ws_size;

    dim3 grid(512);                           // one block per (b, c) plane
    dim3 block(256);
    qconv5x5_kernel<<<grid, block, 0, stream>>>(x, w, out);
}

// Round 5
// 67.936 us; speedup vs baseline: 1.0077x; 1.0077x over previous
//
#include <hip/hip_runtime.h>
#include <hip/hip_bf16.h>
#include <math.h>

// QCONV2d 5x5: out[b,c,h,w] = prod_{p=1..24} cos(x_patch[p] + w[p])
// cos(x+w) = cos(x)cos(w) - sin(x)sin(w): sincos(pixel) once -> LDS float2;
// sincos(w) once per lane -> v_readlane -> wave-uniform SGPRs.
// R3 structure (best measured) with TR=16: 2048 blocks -> 8 blocks/CU ->
// 32 waves/CU (max occupancy) to hide staging/global latency. Each thread:
// 2 adjacent cols x 2 rows; 6-pixel window = 3 aligned ds_read_b128 per
// neighborhood row. Zero pad => (cos,sin)=(1,0) => term = cos(w_p).

#define TR   16                 // output rows per block strip
#define SMR  (TR + 4)           // 20 staged rows
#define SMC  (64 + 4)           // 68 staged cols (544 B/row, 16B-multiple)

__device__ __forceinline__ float rdlane(float v, int lane) {
    return __uint_as_float(__builtin_amdgcn_readlane(__float_as_uint(v), lane));
}

__global__ __launch_bounds__(256)
void qconv5x5_kernel(const float* __restrict__ x, const float* __restrict__ w,
                     float* __restrict__ out)
{
    __shared__ alignas(16) float2 sm[SMR][SMC];   // (cos,sin), 10.9 KB

    const int tid   = threadIdx.x;
    const int bid   = blockIdx.x;
    const int plane = bid >> 2;              // 512 planes
    const int r0    = (bid & 3) * TR;        // strip start row: 0/16/32/48

    // --- w-trig: one sincos per lane, broadcast via readlane -> SGPRs ---
    const int lane = tid & 63;
    float sv, cv;
    __sincosf(w[lane < 25 ? lane : 0], &sv, &cv);
    float cw[25], sw[25];
#pragma unroll
    for (int p = 0; p < 25; ++p) {
        cw[p] = rdlane(cv, p);
        sw[p] = rdlane(sv, p);
    }

    // --- stage rows [r0-2, r0+17], cols [-2,65]; OOB -> (1,0) ---
    const float* xp = x + plane * 64 * 64;
    for (int i = tid; i < SMR * SMC; i += 256) {
        const int rr = i / SMC;
        const int cc = i - rr * SMC;
        const int gr = r0 + rr - 2;
        const int gc = cc - 2;
        float c = 1.0f, s = 0.0f;
        if ((unsigned)gr < 64u && (unsigned)gc < 64u) {
            __sincosf(xp[gr * 64 + gc], &s, &c);
        }
        sm[rr][cc] = make_float2(c, s);
    }
    __syncthreads();

    // --- compute: thread -> col-pair cp (cols 2cp,2cp+1), row-group rq ---
    const int cp = tid & 31;         // 0..31
    const int rq = tid >> 5;         // 0..7, output local rows rq*2, rq*2+1

    float prod[2][2];
#pragma unroll
    for (int ro = 0; ro < 2; ++ro) { prod[ro][0] = 1.f; prod[ro][1] = 1.f; }

    // 6 neighborhood rows feed 2 output rows. Output local row rl = rq*2+ro
    // uses staged rows rl..rl+4 (staged row 0 = global row r0-2).
#pragma unroll
    for (int nr = 0; nr < 6; ++nr) {
        const int tr = rq * 2 + nr;
        const float4* rowp = reinterpret_cast<const float4*>(&sm[tr][0]);
        float4 f0 = rowp[cp], f1 = rowp[cp + 1], f2 = rowp[cp + 2];
        float2 arr6[6] = { make_float2(f0.x, f0.y), make_float2(f0.z, f0.w),
                           make_float2(f1.x, f1.y), make_float2(f1.z, f1.w),
                           make_float2(f2.x, f2.y), make_float2(f2.z, f2.w) };
#pragma unroll
        for (int ro = 0; ro < 2; ++ro) {
            const int di = nr - ro;
            if (di < 0 || di > 4) continue;
#pragma unroll
            for (int dj = 0; dj < 5; ++dj) {
                const int p = di * 5 + dj;
#pragma unroll
                for (int pa = 0; pa < 2; ++pa) {
                    if (p == 0) continue;          // reference skips patch 0
                    const float2 v = arr6[dj + pa];
                    prod[ro][pa] *= fmaf(v.x, cw[p], -(v.y * sw[p]));
                }
            }
        }
    }

    float2* op = reinterpret_cast<float2*>(
        out + plane * 64 * 64 + (r0 + rq * 2) * 64 + 2 * cp);
#pragma unroll
    for (int ro = 0; ro < 2; ++ro)
        op[ro * 32] = make_float2(prod[ro][0], prod[ro][1]);
}

extern "C" void kernel_launch(void* const* d_in, const int* in_sizes, int n_in,
                              void* d_out, int out_size, void* d_ws, size_t ws_size,
                              hipStream_t stream) {
    const float* x = (const float*)d_in[0];   // [32,16,64,64] f32
    const float* w = (const float*)d_in[1];   // [25] f32
    float* out = (float*)d_out;               // [32,16,64,64] f32
    (void)in_sizes; (void)n_in; (void)out_size; (void)d_ws; (void)ws_size;

    dim3 grid(512 * (64 / TR));               // 2048 blocks -> 8/CU, 32 waves/CU
    dim3 block(256);
    qconv5x5_kernel<<<grid, block, 0, stream>>>(x, w, out);
}

// Round 6
// 63.631 us; speedup vs baseline: 1.0759x; 1.0677x over previous
//
#include <hip/hip_runtime.h>
#include <hip/hip_bf16.h>
#include <math.h>

// QCONV2d 5x5: out[b,c,h,w] = prod_{p=1..24} cos(x_patch[p] + w[p])
// cos(x+w) = cos(x)cos(w) - sin(x)sin(w): sincos(pixel) once -> LDS float2;
// sincos(w) once per lane -> v_readlane -> wave-uniform SGPRs.
// R3 compute structure (best measured: TR=32, 1024 blocks, 16 waves/CU,
// 3 aligned ds_read_b128 per neighborhood row). Staging rebuilt: column halo
// is ALWAYS zero-pad (cols -2,-1,64,65 outside the image) -> constant (1,0);
// interior staged via aligned float4 loads with branch-free row-OOB
// (zeroed vector -> sincos(0) = (0,1) = exact pad value).

#define TR   32                 // output rows per block strip
#define SMR  (TR + 4)           // 36 staged rows
#define SMC  (64 + 4)           // 68 staged cols (544 B/row, 16B-multiple)

__device__ __forceinline__ float rdlane(float v, int lane) {
    return __uint_as_float(__builtin_amdgcn_readlane(__float_as_uint(v), lane));
}

__global__ __launch_bounds__(256)
void qconv5x5_kernel(const float* __restrict__ x, const float* __restrict__ w,
                     float* __restrict__ out)
{
    __shared__ alignas(16) float2 sm[SMR][SMC];   // (cos,sin), 19.6 KB

    const int tid   = threadIdx.x;
    const int bid   = blockIdx.x;
    const int plane = bid >> 1;              // 512 planes
    const int r0    = (bid & 1) * TR;        // strip start row: 0 or 32

    // --- w-trig: one sincos per lane, broadcast via readlane -> SGPRs ---
    const int lane = tid & 63;
    float sv, cv;
    __sincosf(w[lane < 25 ? lane : 0], &sv, &cv);
    float cw[25], sw[25];
#pragma unroll
    for (int p = 0; p < 25; ++p) {
        cw[p] = rdlane(cv, p);
        sw[p] = rdlane(sv, p);
    }

    // --- staging ---
    const float* xp = x + plane * 64 * 64;

    // (a) column halo: cols 0,1,66,67 of every staged row = pad (1,0)
    if (tid < SMR * 4) {                     // 144 threads
        const int rr = tid >> 2;
        const int e  = tid & 3;
        const int cc = (e < 2) ? e : 64 + e; // 0,1,66,67
        sm[rr][cc] = make_float2(1.0f, 0.0f);
    }

    // (b) interior: 36 rows x 16 aligned float4 slots; row-OOB -> zeros
    for (int i = tid; i < SMR * 16; i += 256) {
        const int rr = i >> 4;               // 0..35
        const int ss = i & 15;               // 0..15
        const int gr = r0 + rr - 2;
        float4 px = make_float4(0.f, 0.f, 0.f, 0.f);
        if ((unsigned)gr < 64u)
            px = *reinterpret_cast<const float4*>(xp + gr * 64 + 4 * ss);
        float s0, c0, s1, c1, s2, c2, s3, c3;
        __sincosf(px.x, &s0, &c0);
        __sincosf(px.y, &s1, &c1);
        __sincosf(px.z, &s2, &c2);
        __sincosf(px.w, &s3, &c3);
        float2* dst = &sm[rr][4 * ss + 2];   // 16B-aligned
        dst[0] = make_float2(c0, s0);
        dst[1] = make_float2(c1, s1);
        dst[2] = make_float2(c2, s2);
        dst[3] = make_float2(c3, s3);
    }
    __syncthreads();

    // --- compute (R3 structure): col-pair cp, row-group rq (4 rows) ---
    const int cp = tid & 31;         // 0..31
    const int rq = tid >> 5;         // 0..7, output local rows rq*4..rq*4+3

    float prod[4][2];
#pragma unroll
    for (int ro = 0; ro < 4; ++ro) { prod[ro][0] = 1.f; prod[ro][1] = 1.f; }

    // 8 neighborhood rows feed 4 output rows; output local row rl = rq*4+ro
    // uses staged rows rl..rl+4 (staged row 0 = global row r0-2).
#pragma unroll
    for (int nr = 0; nr < 8; ++nr) {
        const int tr = rq * 4 + nr;
        const float4* rowp = reinterpret_cast<const float4*>(&sm[tr][0]);
        float4 f0 = rowp[cp], f1 = rowp[cp + 1], f2 = rowp[cp + 2];
        float2 arr6[6] = { make_float2(f0.x, f0.y), make_float2(f0.z, f0.w),
                           make_float2(f1.x, f1.y), make_float2(f1.z, f1.w),
                           make_float2(f2.x, f2.y), make_float2(f2.z, f2.w) };
#pragma unroll
        for (int ro = 0; ro < 4; ++ro) {
            const int di = nr - ro;
            if (di < 0 || di > 4) continue;
#pragma unroll
            for (int dj = 0; dj < 5; ++dj) {
                const int p = di * 5 + dj;
#pragma unroll
                for (int pa = 0; pa < 2; ++pa) {
                    if (p == 0) continue;          // reference skips patch 0
                    const float2 v = arr6[dj + pa];
                    prod[ro][pa] *= fmaf(v.x, cw[p], -(v.y * sw[p]));
                }
            }
        }
    }

    float2* op = reinterpret_cast<float2*>(
        out + plane * 64 * 64 + (r0 + rq * 4) * 64 + 2 * cp);
#pragma unroll
    for (int ro = 0; ro < 4; ++ro)
        op[ro * 32] = make_float2(prod[ro][0], prod[ro][1]);
}

extern "C" void kernel_launch(void* const* d_in, const int* in_sizes, int n_in,
                              void* d_out, int out_size, void* d_ws, size_t ws_size,
                              hipStream_t stream) {
    const float* x = (const float*)d_in[0];   // [32,16,64,64] f32
    const float* w = (const float*)d_in[1];   // [25] f32
    float* out = (float*)d_out;               // [32,16,64,64] f32
    (void)in_sizes; (void)n_in; (void)out_size; (void)d_ws; (void)ws_size;

    dim3 grid(512 * (64 / TR));               // 1024 blocks
    dim3 block(256);
    qconv5x5_kernel<<<grid, block, 0, stream>>>(x, w, out);
}